// Round 1
// 471.337 us; speedup vs baseline: 1.2505x; 1.2505x over previous
//
#include <hip/hip_runtime.h>
#include <hip/hip_bf16.h>
#include <math.h>

using bf16 = __hip_bfloat16;
typedef _Float16 hf;
typedef hf __attribute__((ext_vector_type(2))) hf2;
typedef __attribute__((ext_vector_type(8))) short short8;
typedef __attribute__((ext_vector_type(4))) float floatx4;

__device__ __forceinline__ float b2f(bf16 x){ return __bfloat162float(x); }
__device__ __forceinline__ bf16 f2b(float x){ return __float2bfloat16(x); }
__device__ __forceinline__ short bfbits(float x){ bf16 t = __float2bfloat16(x); return *(short*)&t; }
__device__ __forceinline__ short hfbits(float x){ hf t = (hf)x; return *(short*)&t; }
__device__ __forceinline__ hf2 u2h2(unsigned u){ return *(hf2*)&u; }

__global__ void fill_const(float* __restrict__ p, float v, int n){
  int i = blockIdx.x*blockDim.x + threadIdx.x;
  if (i < n) p[i] = v;
}

__global__ void conv_f2b(const float* __restrict__ src, bf16* __restrict__ dst, int n){
  int i = blockIdx.x*blockDim.x + threadIdx.x;
  if (i < n) dst[i] = f2b(src[i]);
}

__global__ void conv_f2h(const float* __restrict__ src, short* __restrict__ dst, int n){
  int i = blockIdx.x*blockDim.x + threadIdx.x;
  if (i < n) dst[i] = hfbits(src[i]);
}

// Wcat bf16 [384,256] = [Wq; Wk; Wv|0], bcat f32 [384]
__global__ void build_wcat(const float* __restrict__ Wq, const float* __restrict__ Wk,
                           const float* __restrict__ Wv, const float* __restrict__ bq,
                           const float* __restrict__ bk, const float* __restrict__ bv,
                           bf16* __restrict__ Wcat, float* __restrict__ bcat){
  int i = blockIdx.x*blockDim.x + threadIdx.x;
  if (i >= 384*256) return;
  int r = i >> 8, c = i & 255;
  float v;
  if (r < 128)       v = Wq[r*256 + c];
  else if (r < 256)  v = Wk[(r-128)*256 + c];
  else               v = (c < 128) ? Wv[(r-256)*128 + c] : 0.f;
  Wcat[i] = f2b(v);
  if (i < 384) bcat[i] = (i < 128) ? bq[i] : (i < 256 ? bk[i-128] : bv[i-256]);
}

// ---------------- CSR build ----------------
__global__ void edge_hist(const int* __restrict__ ei, int E, int* __restrict__ deg){
  int e = blockIdx.x*blockDim.x + threadIdx.x;
  if (e >= E) return;
  atomicAdd(&deg[ei[E + e]], 1);
}

// Hierarchical scan, stage 1: per-block (256-elem) reduce of deg -> bsum[block]
__global__ __launch_bounds__(256) void scan_p1(const int* __restrict__ deg, int Nn,
                                               int* __restrict__ bsum){
  int i = blockIdx.x*256 + threadIdx.x;
  int v = (i < Nn) ? deg[i] : 0;
  #pragma unroll
  for (int off=1; off<64; off<<=1) v += __shfl_xor(v, off);
  __shared__ int ws[4];
  if ((threadIdx.x & 63) == 0) ws[threadIdx.x >> 6] = v;
  __syncthreads();
  if (threadIdx.x == 0) bsum[blockIdx.x] = ws[0] + ws[1] + ws[2] + ws[3];
}

// stage 2: single-block exclusive scan of bsum[NB] in place; also writes rowptr[Nn]=E
__global__ __launch_bounds__(1024) void scan_p2(int* __restrict__ bsum, int NB, int E,
                                                int* __restrict__ rowptr, int Nn){
  __shared__ int wsum[16];
  __shared__ int carry_s;
  if (threadIdx.x == 0) carry_s = 0;
  __syncthreads();
  const int lane = threadIdx.x & 63, w = threadIdx.x >> 6;
  for (int base = 0; base < NB; base += 1024){
    int i = base + threadIdx.x;
    int v = (i < NB) ? bsum[i] : 0;
    int s = v;
    #pragma unroll
    for (int off=1; off<64; off<<=1){ int t = __shfl_up(s, off); if (lane >= off) s += t; }
    if (lane == 63) wsum[w] = s;
    __syncthreads();
    if (threadIdx.x < 16){
      int ws = wsum[threadIdx.x];
      #pragma unroll
      for (int off=1; off<16; off<<=1){ int t = __shfl_up(ws, off); if (threadIdx.x >= off) ws += t; }
      wsum[threadIdx.x] = ws;   // inclusive scan of wave totals
    }
    __syncthreads();
    int carry = carry_s;
    int excl = carry + (w ? wsum[w-1] : 0) + (s - v);
    if (i < NB) bsum[i] = excl;
    __syncthreads();
    if (threadIdx.x == 1023) carry_s = carry + wsum[15];
    __syncthreads();
  }
  if (threadIdx.x == 0) rowptr[Nn] = E;
}

// stage 3: per-block exclusive scan of deg tile + block offset -> rowptr, cursor
__global__ __launch_bounds__(256) void scan_p3(const int* __restrict__ deg,
      const int* __restrict__ boff, int Nn,
      int* __restrict__ rowptr, int* __restrict__ cursor){
  int i = blockIdx.x*256 + threadIdx.x;
  int v = (i < Nn) ? deg[i] : 0;
  const int lane = threadIdx.x & 63, w = threadIdx.x >> 6;
  int s = v;
  #pragma unroll
  for (int off=1; off<64; off<<=1){ int t = __shfl_up(s, off); if (lane >= off) s += t; }
  __shared__ int wsum[4];
  if (lane == 63) wsum[w] = s;
  __syncthreads();
  int wpre = 0;
  #pragma unroll
  for (int k=0;k<4;k++) if (k < w) wpre += wsum[k];
  int excl = boff[blockIdx.x] + wpre + (s - v);
  if (i < Nn){ rowptr[i] = excl; cursor[i] = excl; }
}

__global__ void edge_scatter(const int* __restrict__ ei, const int* __restrict__ ety, int E,
                             int* __restrict__ cursor, unsigned* __restrict__ srcet){
  int e = blockIdx.x*blockDim.x + threadIdx.x;
  if (e >= E) return;
  int pos = atomicAdd(&cursor[ei[E + e]], 1);
  srcet[pos] = ((unsigned)ety[e] << 16) | (unsigned)ei[e];
}

// ---------------- QKV GEMM (MFMA): Q f16 [N,128]; KV packed [N,64] lanes of [k0,k1,v0,v1] f16 ----------------
__global__ __launch_bounds__(256) void gemm_qkv(const bf16* __restrict__ nfb, const bf16* __restrict__ qeb,
      const bf16* __restrict__ Wcat, const float* __restrict__ bcat,
      short* __restrict__ Qs, short* __restrict__ KVs, int M){
  constexpr int BK=32, LDT=40, K=256;
  __shared__ short As[64*LDT];
  __shared__ short Bs[64*LDT];
  const int tid  = threadIdx.x;
  const int lane = tid & 63;
  const int wave = tid >> 6;
  const int wm = (wave >> 1) * 32, wn = (wave & 1) * 32;
  const long m0 = (long)blockIdx.x * 64;
  const int  n0 = blockIdx.y * 64;
  floatx4 acc00 = {0.f,0.f,0.f,0.f}, acc01 = {0.f,0.f,0.f,0.f};
  floatx4 acc10 = {0.f,0.f,0.f,0.f}, acc11 = {0.f,0.f,0.f,0.f};
  const int srow = tid >> 2, scg = (tid & 3) * 8;
  const int r = lane & 15, q = lane >> 4;
  const short* Ag = (const short*)nfb;
  const short* Qg = (const short*)qeb;
  const short* Bg = (const short*)Wcat;
  for (int k0 = 0; k0 < K; k0 += BK){
    short8 va = {0,0,0,0,0,0,0,0};
    if (k0 < 128){
      long ar = m0 + srow;
      if (ar < M) va = *(const short8*)(Ag + ar*128 + k0 + scg);
    } else {
      va = *(const short8*)(Qg + (k0-128) + scg);   // row-independent broadcast
    }
    *(short8*)(&As[srow*LDT + scg]) = va;
    *(short8*)(&Bs[srow*LDT + scg]) = *(const short8*)(Bg + (long)(n0 + srow)*K + k0 + scg);
    __syncthreads();
    short8 a0 = *(const short8*)(&As[(wm      + r)*LDT + q*8]);
    short8 a1 = *(const short8*)(&As[(wm + 16 + r)*LDT + q*8]);
    short8 b0 = *(const short8*)(&Bs[(wn      + r)*LDT + q*8]);
    short8 b1 = *(const short8*)(&Bs[(wn + 16 + r)*LDT + q*8]);
    acc00 = __builtin_amdgcn_mfma_f32_16x16x32_bf16(a0, b0, acc00, 0, 0, 0);
    acc01 = __builtin_amdgcn_mfma_f32_16x16x32_bf16(a0, b1, acc01, 0, 0, 0);
    acc10 = __builtin_amdgcn_mfma_f32_16x16x32_bf16(a1, b0, acc10, 0, 0, 0);
    acc11 = __builtin_amdgcn_mfma_f32_16x16x32_bf16(a1, b1, acc11, 0, 0, 0);
    __syncthreads();
  }
  #pragma unroll
  for (int i=0;i<2;i++)
  #pragma unroll
  for (int j=0;j<2;j++){
    floatx4 av = (i==0) ? ((j==0)?acc00:acc01) : ((j==0)?acc10:acc11);
    int col = n0 + wn + j*16 + r;
    float bsv = bcat[col];
    #pragma unroll
    for (int g=0; g<4; g++){
      long row = m0 + wm + i*16 + q*4 + g;
      if (row < M){
        short bits = hfbits(av[g] + bsv);
        if (col < 128)      Qs[row*128 + col] = bits;
        else if (col < 256){ int d = col - 128; KVs[row*256 + ((d>>1)<<2) + (d&1)] = bits; }
        else               { int d = col - 256; KVs[row*256 + ((d>>1)<<2) + 2 + (d&1)] = bits; }
      }
    }
  }
}

// ---------------- generic GEMM (MFMA, used for Wo): C f32 = A_bf16 @ B_bf16^T + bias ----------------
__global__ __launch_bounds__(256) void gemm_bt(const bf16* __restrict__ A, const bf16* __restrict__ B,
      const float* __restrict__ bias, float* __restrict__ C, int M, int N, int K){
  constexpr int BK=32, LDT=40;
  __shared__ short As[64*LDT];
  __shared__ short Bs[64*LDT];
  const int tid  = threadIdx.x;
  const int lane = tid & 63;
  const int wave = tid >> 6;
  const int wm = (wave >> 1) * 32, wn = (wave & 1) * 32;
  const long m0 = (long)blockIdx.x * 64;
  const int  n0 = blockIdx.y * 64;
  floatx4 acc00 = {0.f,0.f,0.f,0.f}, acc01 = {0.f,0.f,0.f,0.f};
  floatx4 acc10 = {0.f,0.f,0.f,0.f}, acc11 = {0.f,0.f,0.f,0.f};
  const int srow = tid >> 2, scg = (tid & 3) * 8;
  const int r = lane & 15, q = lane >> 4;
  const short* Ag = (const short*)A;
  const short* Bg = (const short*)B;
  for (int k0 = 0; k0 < K; k0 += BK){
    short8 va = {0,0,0,0,0,0,0,0};
    long ar = m0 + srow;
    if (ar < M) va = *(const short8*)(Ag + ar*K + k0 + scg);
    *(short8*)(&As[srow*LDT + scg]) = va;
    *(short8*)(&Bs[srow*LDT + scg]) = *(const short8*)(Bg + (long)(n0 + srow)*K + k0 + scg);
    __syncthreads();
    short8 a0 = *(const short8*)(&As[(wm      + r)*LDT + q*8]);
    short8 a1 = *(const short8*)(&As[(wm + 16 + r)*LDT + q*8]);
    short8 b0 = *(const short8*)(&Bs[(wn      + r)*LDT + q*8]);
    short8 b1 = *(const short8*)(&Bs[(wn + 16 + r)*LDT + q*8]);
    acc00 = __builtin_amdgcn_mfma_f32_16x16x32_bf16(a0, b0, acc00, 0, 0, 0);
    acc01 = __builtin_amdgcn_mfma_f32_16x16x32_bf16(a0, b1, acc01, 0, 0, 0);
    acc10 = __builtin_amdgcn_mfma_f32_16x16x32_bf16(a1, b0, acc10, 0, 0, 0);
    acc11 = __builtin_amdgcn_mfma_f32_16x16x32_bf16(a1, b1, acc11, 0, 0, 0);
    __syncthreads();
  }
  #pragma unroll
  for (int i=0;i<2;i++)
  #pragma unroll
  for (int j=0;j<2;j++){
    floatx4 av = (i==0) ? ((j==0)?acc00:acc01) : ((j==0)?acc10:acc11);
    int col = n0 + wn + j*16 + r;
    float bsv = bias[col];
    #pragma unroll
    for (int g=0; g<4; g++){
      long row = m0 + wm + i*16 + q*4 + g;
      if (row < M) C[row*(long)N + col] = av[g] + bsv;
    }
  }
}

// ---------------- attention: 1 wave per node, lane owns dims {2l,2l+1} as f16 pairs ----------------
__global__ __launch_bounds__(256) void attn_agg(const unsigned* __restrict__ Qh,
     const uint2* __restrict__ KVh, const unsigned* __restrict__ Rh,
     const int* __restrict__ rowptr, const unsigned* __restrict__ srcet,
     unsigned* __restrict__ agg, int Nn){
  const int w = threadIdx.x >> 6, l = threadIdx.x & 63;
  const int n = blockIdx.x*4 + w;
  if (n >= Nn) return;
  hf2 q2 = u2h2(Qh[(long)n*64 + l]);
  int beg = rowptr[n], end = rowptr[n+1];
  float acc0 = 0.f, acc1 = 0.f, denom = 0.f;
  for (int c = beg; c < end; c += 64){
    int cnt = end - c; if (cnt > 64) cnt = 64;
    unsigned se_l = (c + l < end) ? srcet[c + l] : 0u;
    for (int j = 0; j < cnt; ++j){
      unsigned se = __shfl(se_l, j);
      int src = se & 0xFFFF;
      int et  = se >> 16;
      uint2 kv = KVh[(long)src*64 + l];
      hf2 kb = u2h2(kv.x) + u2h2(Rh[et*64 + l]);     // v_pk_add_f16
#if __has_builtin(__builtin_amdgcn_fdot2)
      float p = __builtin_amdgcn_fdot2(q2, kb, 0.f, false);
#else
      float p = fmaf((float)q2.y, (float)kb.y, (float)q2.x * (float)kb.x);
#endif
      p += __shfl_xor(p, 1); p += __shfl_xor(p, 2); p += __shfl_xor(p, 4);
      float es = __expf(p * 0.25f);
      denom += es;
      hf2 v2 = u2h2(kv.y);
      acc0 = fmaf(es, (float)v2.x, acc0);
      acc1 = fmaf(es, (float)v2.y, acc1);
    }
  }
  float inv = 1.f / (denom + 1e-8f);
  unsigned out = ((unsigned)(unsigned short)bfbits(acc1 * inv) << 16)
               |  (unsigned)(unsigned short)bfbits(acc0 * inv);
  agg[(long)n*64 + l] = out;
}

// ---------------- residual + LN1: x = LN(nf + attn), out bf16 ----------------
__global__ __launch_bounds__(128) void ln_add1(const float* __restrict__ nf, const float* __restrict__ attn,
     const float* __restrict__ g, const float* __restrict__ b, bf16* __restrict__ xout){
  long n = blockIdx.x; int t = threadIdx.x;
  float y = nf[n*128 + t] + attn[n*128 + t];
  float s = y, s2 = y*y;
  #pragma unroll
  for (int off=32; off>0; off>>=1){ s += __shfl_xor(s, off); s2 += __shfl_xor(s2, off); }
  __shared__ float ps[4];
  if ((t & 63) == 0){ ps[(t>>6)*2] = s; ps[(t>>6)*2+1] = s2; }
  __syncthreads();
  float tot = ps[0] + ps[2], tot2 = ps[1] + ps[3];
  float mu = tot * (1.f/128.f);
  float var = tot2 * (1.f/128.f) - mu*mu;
  float rs = rsqrtf(var + 1e-5f);
  xout[n*128 + t] = f2b((y - mu)*rs*g[t] + b[t]);
}

// ---------------- fused FFN (MFMA), h split in 2 halves -> 68.6 KB LDS -> 2 blocks/CU ----------------
__global__ __launch_bounds__(256) void ffn_fused(const bf16* __restrict__ X, const bf16* __restrict__ W1,
    const float* __restrict__ b1, const bf16* __restrict__ W2, const float* __restrict__ b2,
    float* __restrict__ Out, int M){
  __shared__ short Xs[64*136];
  __shared__ short Hs[64*264];
  __shared__ short Ws[64*136];
  const int tid = threadIdx.x, lane = tid & 63, wave = tid >> 6;
  const int r = lane & 15, q = lane >> 4;
  const int wm = (wave >> 1) * 32, wn = (wave & 1) * 32;
  const long m0 = (long)blockIdx.x * 64;
  const short* Xg  = (const short*)X;
  const short* W1g = (const short*)W1;
  const short* W2g = (const short*)W2;
  #pragma unroll
  for (int c=0;c<4;c++){
    int idx = c*256 + tid, row = idx >> 4, ch = (idx & 15) * 8;
    short8 v = {0,0,0,0,0,0,0,0};
    long ar = m0 + row;
    if (ar < M) v = *(const short8*)(Xg + ar*128 + ch);
    *(short8*)(&Xs[row*136 + ch]) = v;
  }
  const int wn2 = (wave & 1) * 64;
  floatx4 o[2][4];
  #pragma unroll
  for (int i=0;i<2;i++)
  #pragma unroll
  for (int j=0;j<4;j++) o[i][j] = (floatx4){0.f,0.f,0.f,0.f};
  for (int half = 0; half < 2; ++half){
    const int hb = half * 256;
    for (int c0 = 0; c0 < 256; c0 += 64){
      #pragma unroll
      for (int c=0;c<4;c++){
        int idx = c*256 + tid, row = idx >> 4, ch = (idx & 15) * 8;
        *(short8*)(&Ws[row*136 + ch]) = *(const short8*)(W1g + (long)(hb + c0 + row)*128 + ch);
      }
      __syncthreads();
      floatx4 h00 = {0.f,0.f,0.f,0.f}, h01 = {0.f,0.f,0.f,0.f};
      floatx4 h10 = {0.f,0.f,0.f,0.f}, h11 = {0.f,0.f,0.f,0.f};
      #pragma unroll
      for (int k0 = 0; k0 < 128; k0 += 32){
        short8 a0 = *(const short8*)(&Xs[(wm      + r)*136 + k0 + q*8]);
        short8 a1 = *(const short8*)(&Xs[(wm + 16 + r)*136 + k0 + q*8]);
        short8 b0 = *(const short8*)(&Ws[(wn      + r)*136 + k0 + q*8]);
        short8 bv = *(const short8*)(&Ws[(wn + 16 + r)*136 + k0 + q*8]);
        h00 = __builtin_amdgcn_mfma_f32_16x16x32_bf16(a0, b0, h00, 0, 0, 0);
        h01 = __builtin_amdgcn_mfma_f32_16x16x32_bf16(a0, bv, h01, 0, 0, 0);
        h10 = __builtin_amdgcn_mfma_f32_16x16x32_bf16(a1, b0, h10, 0, 0, 0);
        h11 = __builtin_amdgcn_mfma_f32_16x16x32_bf16(a1, bv, h11, 0, 0, 0);
      }
      #pragma unroll
      for (int i=0;i<2;i++)
      #pragma unroll
      for (int j=0;j<2;j++){
        floatx4 av = (i==0) ? ((j==0)?h00:h01) : ((j==0)?h10:h11);
        int col = wn + j*16 + r;
        float bb = b1[hb + c0 + col];
        #pragma unroll
        for (int g=0; g<4; g++){
          int row = wm + i*16 + q*4 + g;
          float v = av[g] + bb;
          v = 0.5f * v * (1.f + erff(v * 0.70710678118f));   // exact GELU
          Hs[row*264 + c0 + col] = bfbits(v);
        }
      }
      __syncthreads();
    }
    for (int k0 = 0; k0 < 256; k0 += 32){
      #pragma unroll
      for (int c=0;c<2;c++){
        int idx = c*256 + tid, row = idx >> 2, ch = (idx & 3) * 8;
        *(short8*)(&Ws[row*40 + ch]) = *(const short8*)(W2g + (long)row*512 + hb + k0 + ch);
      }
      __syncthreads();
      short8 a0 = *(const short8*)(&Hs[(wm      + r)*264 + k0 + q*8]);
      short8 a1 = *(const short8*)(&Hs[(wm + 16 + r)*264 + k0 + q*8]);
      #pragma unroll
      for (int j=0;j<4;j++){
        short8 bj = *(const short8*)(&Ws[(wn2 + j*16 + r)*40 + q*8]);
        o[0][j] = __builtin_amdgcn_mfma_f32_16x16x32_bf16(a0, bj, o[0][j], 0, 0, 0);
        o[1][j] = __builtin_amdgcn_mfma_f32_16x16x32_bf16(a1, bj, o[1][j], 0, 0, 0);
      }
      __syncthreads();
    }
  }
  #pragma unroll
  for (int i=0;i<2;i++)
  #pragma unroll
  for (int j=0;j<4;j++){
    int col = wn2 + j*16 + r;
    float bb = b2[col];
    #pragma unroll
    for (int g=0; g<4; g++){
      long row = m0 + wm + i*16 + q*4 + g;
      if (row < M) Out[row*128 + col] = o[i][j][g] + bb;
    }
  }
}

// ---------------- residual + LN2: out = LN(x + ffo), f32 out ----------------
__global__ __launch_bounds__(128) void ln_add2(const bf16* __restrict__ X, const float* __restrict__ ffo,
     const float* __restrict__ g, const float* __restrict__ b, float* __restrict__ out){
  long n = blockIdx.x; int t = threadIdx.x;
  float y = b2f(X[n*128 + t]) + ffo[n*128 + t];
  float s = y, s2 = y*y;
  #pragma unroll
  for (int off=32; off>0; off>>=1){ s += __shfl_xor(s, off); s2 += __shfl_xor(s2, off); }
  __shared__ float ps[4];
  if ((t & 63) == 0){ ps[(t>>6)*2] = s; ps[(t>>6)*2+1] = s2; }
  __syncthreads();
  float tot = ps[0] + ps[2], tot2 = ps[1] + ps[3];
  float mu = tot * (1.f/128.f);
  float var = tot2 * (1.f/128.f) - mu*mu;
  float rs = rsqrtf(var + 1e-5f);
  out[n*128 + t] = (y - mu)*rs*g[t] + b[t];
}

// ---------------- relational interaction layer (R=100, naive f32) ----------------
__device__ __forceinline__ float dotf(const float* __restrict__ s, const float* __restrict__ w, int n){
  float acc = 0.f;
  const float4* w4 = (const float4*)w;
  #pragma unroll 4
  for (int j = 0; j < (n >> 2); ++j){
    float4 wv = w4[j];
    acc += s[4*j]*wv.x + s[4*j+1]*wv.y + s[4*j+2]*wv.z + s[4*j+3]*wv.w;
  }
  return acc;
}

__global__ __launch_bounds__(128) void rel_layer(const float* __restrict__ rel, const float* __restrict__ relW,
    const float* __restrict__ relb, const float* __restrict__ Wc, const float* __restrict__ bc,
    const float* __restrict__ gn, const float* __restrict__ bn, float* __restrict__ out){
  int rr = blockIdx.x, t = threadIdx.x;
  __shared__ float rrow[128];
  __shared__ float comb[512];
  rrow[t] = rel[(long)rr*128 + t];
  __syncthreads();
  #pragma unroll
  for (int k=0;k<4;k++){
    comb[k*128 + t] = dotf(rrow, relW + ((long)(k*128) + t)*128, 128) + relb[k*128 + t];
  }
  __syncthreads();
  float c2 = dotf(comb, Wc + (long)t*512, 512) + bc[t];
  float y = rrow[t] + c2;
  float s = y, s2 = y*y;
  #pragma unroll
  for (int off=32; off>0; off>>=1){ s += __shfl_xor(s, off); s2 += __shfl_xor(s2, off); }
  __shared__ float ps[4];
  if ((t & 63) == 0){ ps[(t>>6)*2] = s; ps[(t>>6)*2+1] = s2; }
  __syncthreads();
  float tot = ps[0] + ps[2], tot2 = ps[1] + ps[3];
  float mu = tot * (1.f/128.f);
  float var = tot2 * (1.f/128.f) - mu*mu;
  float rs = rsqrtf(var + 1e-5f);
  out[(long)rr*128 + t] = (y - mu)*rs*gn[t] + bn[t];
}

extern "C" void kernel_launch(void* const* d_in, const int* in_sizes, int n_in,
                              void* d_out, int out_size, void* d_ws, size_t ws_size,
                              hipStream_t stream){
  const int H = 128;
  auto S = [&](int i){ return in_sizes[i]; };
  bool ok = (n_in == 27);
  if (ok){
    ok = ok && S(1)==H && (S(0)%H)==0 && S(2)==2*S(3) && (S(4)%H)==0;
    ok = ok && S(5)==2*H*H && S(7)==2*H*H && S(9)==H*H && S(11)==H*H;
    ok = ok && S(17)==4*H*H && S(19)==4*H*H && S(21)==4*H*H && S(23)==4*H*H;
    ok = ok && out_size == S(0) + S(4);
  }
  if (!ok){
    fill_const<<<(out_size + 255)/256, 256, 0, stream>>>((float*)d_out, 100.0f, out_size);
    return;
  }

  const float* nf   = (const float*)d_in[0];
  const float* qe   = (const float*)d_in[1];
  const int*   ei   = (const int*)  d_in[2];
  const int*   ety  = (const int*)  d_in[3];
  const float* rel  = (const float*)d_in[4];
  const float* Wq   = (const float*)d_in[5];
  const float* bq   = (const float*)d_in[6];
  const float* Wk   = (const float*)d_in[7];
  const float* bk   = (const float*)d_in[8];
  const float* Wv   = (const float*)d_in[9];
  const float* bv   = (const float*)d_in[10];
  const float* Wo   = (const float*)d_in[11];
  const float* bo   = (const float*)d_in[12];
  const float* n1g  = (const float*)d_in[13];
  const float* n1b  = (const float*)d_in[14];
  const float* n2g  = (const float*)d_in[15];
  const float* n2b  = (const float*)d_in[16];
  const float* W1   = (const float*)d_in[17];
  const float* b1   = (const float*)d_in[18];
  const float* W2   = (const float*)d_in[19];
  const float* b2v  = (const float*)d_in[20];
  const float* relW = (const float*)d_in[21];
  const float* relbp= (const float*)d_in[22];
  const float* Wc   = (const float*)d_in[23];
  const float* bc   = (const float*)d_in[24];
  const float* rng  = (const float*)d_in[25];
  const float* rnb  = (const float*)d_in[26];

  const int N = in_sizes[0] / 128;
  const int E = in_sizes[2] / 2;
  const int R = in_sizes[4] / 128;

  char* ws = (char*)d_ws;
  size_t off = 0;
  auto alloc = [&](size_t bytes)->char*{
    char* p = ws + off; off = (off + bytes + 255) & ~(size_t)255; return p;
  };
  // regNA: nfb bf16 [N,128] -> aggp bf16 [N,128] (nfb dead after gemm_qkv)
  char*     regNA  = alloc((size_t)N * 256);
  // regKV: KVh uint2 [N,64] -> attn f32 [N,128] -> ffo f32 [N,128]
  char*     regKV  = alloc((size_t)N * 512);
  unsigned* Qh     = (unsigned*)alloc((size_t)N * 256);   // f16 pairs; dead after attn_agg
  bf16*     xlb    = (bf16*)    alloc((size_t)N * 256);
  bf16*     qeb    = (bf16*)    alloc(256);
  bf16*     Wcat   = (bf16*)    alloc((size_t)384*256*2);
  float*    bcat   = (float*)   alloc(384*4);
  bf16*     Wob    = (bf16*)    alloc((size_t)128*128*2);
  bf16*     W1b    = (bf16*)    alloc((size_t)512*128*2);
  bf16*     W2b    = (bf16*)    alloc((size_t)128*512*2);
  short*    Rh     = (short*)   alloc((size_t)R*128*2);   // rel embeddings f16
  int*      deg    = (int*)     alloc((size_t)N * 4);
  int*      rowptr = (int*)     alloc((size_t)(N+1) * 4);
  int*      cursor = (int*)     alloc((size_t)N * 4);
  unsigned* srcet  = (unsigned*)alloc((size_t)E * 4);
  const int NB = (N + 255) / 256;
  int*      bsum   = (int*)     alloc((size_t)NB * 4);

  if (off > ws_size){
    fill_const<<<(out_size + 255)/256, 256, 0, stream>>>((float*)d_out, 50.0f, out_size);
    return;
  }

  bf16*     nfb  = (bf16*)regNA;
  unsigned* aggp = (unsigned*)regNA;  // bf16 pairs, overlays nfb
  uint2*    KVh  = (uint2*)regKV;
  float*    attn = (float*)regKV;     // overlays KVh (dead after attn_agg)
  float*    ffo  = (float*)regKV;     // overlays attn (dead after ln_add1)
  float*    outx = (float*)d_out;
  float*    outr = (float*)d_out + (size_t)N*128;

  // conversions
  conv_f2b<<<(N*128 + 255)/256, 256, 0, stream>>>(nf, nfb, N*128);
  conv_f2b<<<1, 128, 0, stream>>>(qe, qeb, 128);
  build_wcat<<<(384*256 + 255)/256, 256, 0, stream>>>(Wq, Wk, Wv, bq, bk, bv, Wcat, bcat);
  conv_f2b<<<(128*128 + 255)/256, 256, 0, stream>>>(Wo, Wob, 128*128);
  conv_f2b<<<(512*128 + 255)/256, 256, 0, stream>>>(W1, W1b, 512*128);
  conv_f2b<<<(128*512 + 255)/256, 256, 0, stream>>>(W2, W2b, 128*512);
  conv_f2h<<<(R*128 + 255)/256, 256, 0, stream>>>(rel, Rh, R*128);

  // CSR (hierarchical scan: per-block reduce -> scan block sums -> per-block scan)
  hipMemsetAsync(deg, 0, (size_t)N*4, stream);
  edge_hist<<<(E + 255)/256, 256, 0, stream>>>(ei, E, deg);
  scan_p1<<<NB, 256, 0, stream>>>(deg, N, bsum);
  scan_p2<<<1, 1024, 0, stream>>>(bsum, NB, E, rowptr, N);
  scan_p3<<<NB, 256, 0, stream>>>(deg, bsum, N, rowptr, cursor);
  edge_scatter<<<(E + 255)/256, 256, 0, stream>>>(ei, ety, E, cursor, srcet);

  // pipeline
  dim3 g1((N + 63)/64, 6);
  gemm_qkv<<<g1, 256, 0, stream>>>(nfb, qeb, Wcat, bcat, (short*)Qh, (short*)KVh, N);
  attn_agg<<<(N + 3)/4, 256, 0, stream>>>(Qh, KVh, (const unsigned*)Rh, rowptr, srcet, aggp, N);
  dim3 g2((N + 63)/64, 2);
  gemm_bt<<<g2, 256, 0, stream>>>((const bf16*)aggp, Wob, bo, attn, N, 128, 128);
  ln_add1<<<N, 128, 0, stream>>>(nf, attn, n1g, n1b, xlb);
  ffn_fused<<<(N + 63)/64, 256, 0, stream>>>(xlb, W1b, b1, W2b, b2v, ffo, N);
  ln_add2<<<N, 128, 0, stream>>>(xlb, ffo, n2g, n2b, outx);
  rel_layer<<<R, 128, 0, stream>>>(rel, relW, relbp, Wc, bc, rng, rnb, outr);
}

// Round 2
// 452.723 us; speedup vs baseline: 1.3019x; 1.0411x over previous
//
#include <hip/hip_runtime.h>
#include <hip/hip_bf16.h>
#include <math.h>

using bf16 = __hip_bfloat16;
typedef _Float16 hf;
typedef hf __attribute__((ext_vector_type(2))) hf2;
typedef __attribute__((ext_vector_type(8))) short short8;
typedef __attribute__((ext_vector_type(4))) float floatx4;

__device__ __forceinline__ float b2f(bf16 x){ return __bfloat162float(x); }
__device__ __forceinline__ bf16 f2b(float x){ return __float2bfloat16(x); }
__device__ __forceinline__ short bfbits(float x){ bf16 t = __float2bfloat16(x); return *(short*)&t; }
__device__ __forceinline__ short hfbits(float x){ hf t = (hf)x; return *(short*)&t; }
__device__ __forceinline__ hf2 u2h2(unsigned u){ return *(hf2*)&u; }

__global__ void fill_const(float* __restrict__ p, float v, int n){
  int i = blockIdx.x*blockDim.x + threadIdx.x;
  if (i < n) p[i] = v;
}

__global__ void conv_f2b(const float* __restrict__ src, bf16* __restrict__ dst, int n){
  int i = blockIdx.x*blockDim.x + threadIdx.x;
  if (i < n) dst[i] = f2b(src[i]);
}

__global__ void conv_f2h(const float* __restrict__ src, short* __restrict__ dst, int n){
  int i = blockIdx.x*blockDim.x + threadIdx.x;
  if (i < n) dst[i] = hfbits(src[i]);
}

// Wcat bf16 [384,256] = [Wq; Wk; Wv|0], bcat f32 [384]
__global__ void build_wcat(const float* __restrict__ Wq, const float* __restrict__ Wk,
                           const float* __restrict__ Wv, const float* __restrict__ bq,
                           const float* __restrict__ bk, const float* __restrict__ bv,
                           bf16* __restrict__ Wcat, float* __restrict__ bcat){
  int i = blockIdx.x*blockDim.x + threadIdx.x;
  if (i >= 384*256) return;
  int r = i >> 8, c = i & 255;
  float v;
  if (r < 128)       v = Wq[r*256 + c];
  else if (r < 256)  v = Wk[(r-128)*256 + c];
  else               v = (c < 128) ? Wv[(r-256)*128 + c] : 0.f;
  Wcat[i] = f2b(v);
  if (i < 384) bcat[i] = (i < 128) ? bq[i] : (i < 256 ? bk[i-128] : bv[i-256]);
}

// ---------------- CSR build ----------------
__global__ void edge_hist(const int* __restrict__ ei, int E, int* __restrict__ deg){
  int e = blockIdx.x*blockDim.x + threadIdx.x;
  if (e >= E) return;
  atomicAdd(&deg[ei[E + e]], 1);
}

// Hierarchical scan, stage 1: per-block (256-elem) reduce of deg -> bsum[block]
__global__ __launch_bounds__(256) void scan_p1(const int* __restrict__ deg, int Nn,
                                               int* __restrict__ bsum){
  int i = blockIdx.x*256 + threadIdx.x;
  int v = (i < Nn) ? deg[i] : 0;
  #pragma unroll
  for (int off=1; off<64; off<<=1) v += __shfl_xor(v, off);
  __shared__ int ws[4];
  if ((threadIdx.x & 63) == 0) ws[threadIdx.x >> 6] = v;
  __syncthreads();
  if (threadIdx.x == 0) bsum[blockIdx.x] = ws[0] + ws[1] + ws[2] + ws[3];
}

// stage 2: single-block exclusive scan of bsum[NB] in place; also writes rowptr[Nn]=E
__global__ __launch_bounds__(1024) void scan_p2(int* __restrict__ bsum, int NB, int E,
                                                int* __restrict__ rowptr, int Nn){
  __shared__ int wsum[16];
  __shared__ int carry_s;
  if (threadIdx.x == 0) carry_s = 0;
  __syncthreads();
  const int lane = threadIdx.x & 63, w = threadIdx.x >> 6;
  for (int base = 0; base < NB; base += 1024){
    int i = base + threadIdx.x;
    int v = (i < NB) ? bsum[i] : 0;
    int s = v;
    #pragma unroll
    for (int off=1; off<64; off<<=1){ int t = __shfl_up(s, off); if (lane >= off) s += t; }
    if (lane == 63) wsum[w] = s;
    __syncthreads();
    if (threadIdx.x < 16){
      int ws = wsum[threadIdx.x];
      #pragma unroll
      for (int off=1; off<16; off<<=1){ int t = __shfl_up(ws, off); if (threadIdx.x >= off) ws += t; }
      wsum[threadIdx.x] = ws;   // inclusive scan of wave totals
    }
    __syncthreads();
    int carry = carry_s;
    int excl = carry + (w ? wsum[w-1] : 0) + (s - v);
    if (i < NB) bsum[i] = excl;
    __syncthreads();
    if (threadIdx.x == 1023) carry_s = carry + wsum[15];
    __syncthreads();
  }
  if (threadIdx.x == 0) rowptr[Nn] = E;
}

// stage 3: per-block exclusive scan of deg tile + block offset -> rowptr, cursor
__global__ __launch_bounds__(256) void scan_p3(const int* __restrict__ deg,
      const int* __restrict__ boff, int Nn,
      int* __restrict__ rowptr, int* __restrict__ cursor){
  int i = blockIdx.x*256 + threadIdx.x;
  int v = (i < Nn) ? deg[i] : 0;
  const int lane = threadIdx.x & 63, w = threadIdx.x >> 6;
  int s = v;
  #pragma unroll
  for (int off=1; off<64; off<<=1){ int t = __shfl_up(s, off); if (lane >= off) s += t; }
  __shared__ int wsum[4];
  if (lane == 63) wsum[w] = s;
  __syncthreads();
  int wpre = 0;
  #pragma unroll
  for (int k=0;k<4;k++) if (k < w) wpre += wsum[k];
  int excl = boff[blockIdx.x] + wpre + (s - v);
  if (i < Nn){ rowptr[i] = excl; cursor[i] = excl; }
}

__global__ void edge_scatter(const int* __restrict__ ei, const int* __restrict__ ety, int E,
                             int* __restrict__ cursor, unsigned* __restrict__ srcet){
  int e = blockIdx.x*blockDim.x + threadIdx.x;
  if (e >= E) return;
  int pos = atomicAdd(&cursor[ei[E + e]], 1);
  srcet[pos] = ((unsigned)ety[e] << 16) | (unsigned)ei[e];
}

// ---------------- QKV GEMM (MFMA): Q f16 [N,128]; KV packed [N,64] lanes of [k0,k1,v0,v1] f16 ----------------
__global__ __launch_bounds__(256) void gemm_qkv(const bf16* __restrict__ nfb, const bf16* __restrict__ qeb,
      const bf16* __restrict__ Wcat, const float* __restrict__ bcat,
      short* __restrict__ Qs, short* __restrict__ KVs, int M){
  constexpr int BK=32, LDT=40, K=256;
  __shared__ short As[64*LDT];
  __shared__ short Bs[64*LDT];
  const int tid  = threadIdx.x;
  const int lane = tid & 63;
  const int wave = tid >> 6;
  const int wm = (wave >> 1) * 32, wn = (wave & 1) * 32;
  const long m0 = (long)blockIdx.x * 64;
  const int  n0 = blockIdx.y * 64;
  floatx4 acc00 = {0.f,0.f,0.f,0.f}, acc01 = {0.f,0.f,0.f,0.f};
  floatx4 acc10 = {0.f,0.f,0.f,0.f}, acc11 = {0.f,0.f,0.f,0.f};
  const int srow = tid >> 2, scg = (tid & 3) * 8;
  const int r = lane & 15, q = lane >> 4;
  const short* Ag = (const short*)nfb;
  const short* Qg = (const short*)qeb;
  const short* Bg = (const short*)Wcat;
  for (int k0 = 0; k0 < K; k0 += BK){
    short8 va = {0,0,0,0,0,0,0,0};
    if (k0 < 128){
      long ar = m0 + srow;
      if (ar < M) va = *(const short8*)(Ag + ar*128 + k0 + scg);
    } else {
      va = *(const short8*)(Qg + (k0-128) + scg);   // row-independent broadcast
    }
    *(short8*)(&As[srow*LDT + scg]) = va;
    *(short8*)(&Bs[srow*LDT + scg]) = *(const short8*)(Bg + (long)(n0 + srow)*K + k0 + scg);
    __syncthreads();
    short8 a0 = *(const short8*)(&As[(wm      + r)*LDT + q*8]);
    short8 a1 = *(const short8*)(&As[(wm + 16 + r)*LDT + q*8]);
    short8 b0 = *(const short8*)(&Bs[(wn      + r)*LDT + q*8]);
    short8 b1 = *(const short8*)(&Bs[(wn + 16 + r)*LDT + q*8]);
    acc00 = __builtin_amdgcn_mfma_f32_16x16x32_bf16(a0, b0, acc00, 0, 0, 0);
    acc01 = __builtin_amdgcn_mfma_f32_16x16x32_bf16(a0, b1, acc01, 0, 0, 0);
    acc10 = __builtin_amdgcn_mfma_f32_16x16x32_bf16(a1, b0, acc10, 0, 0, 0);
    acc11 = __builtin_amdgcn_mfma_f32_16x16x32_bf16(a1, b1, acc11, 0, 0, 0);
    __syncthreads();
  }
  #pragma unroll
  for (int i=0;i<2;i++)
  #pragma unroll
  for (int j=0;j<2;j++){
    floatx4 av = (i==0) ? ((j==0)?acc00:acc01) : ((j==0)?acc10:acc11);
    int col = n0 + wn + j*16 + r;
    float bsv = bcat[col];
    #pragma unroll
    for (int g=0; g<4; g++){
      long row = m0 + wm + i*16 + q*4 + g;
      if (row < M){
        short bits = hfbits(av[g] + bsv);
        if (col < 128)      Qs[row*128 + col] = bits;
        else if (col < 256){ int d = col - 128; KVs[row*256 + ((d>>1)<<2) + (d&1)] = bits; }
        else               { int d = col - 256; KVs[row*256 + ((d>>1)<<2) + 2 + (d&1)] = bits; }
      }
    }
  }
}

// ---------------- generic GEMM (MFMA, used for Wo): C f32 = A_bf16 @ B_bf16^T + bias ----------------
__global__ __launch_bounds__(256) void gemm_bt(const bf16* __restrict__ A, const bf16* __restrict__ B,
      const float* __restrict__ bias, float* __restrict__ C, int M, int N, int K){
  constexpr int BK=32, LDT=40;
  __shared__ short As[64*LDT];
  __shared__ short Bs[64*LDT];
  const int tid  = threadIdx.x;
  const int lane = tid & 63;
  const int wave = tid >> 6;
  const int wm = (wave >> 1) * 32, wn = (wave & 1) * 32;
  const long m0 = (long)blockIdx.x * 64;
  const int  n0 = blockIdx.y * 64;
  floatx4 acc00 = {0.f,0.f,0.f,0.f}, acc01 = {0.f,0.f,0.f,0.f};
  floatx4 acc10 = {0.f,0.f,0.f,0.f}, acc11 = {0.f,0.f,0.f,0.f};
  const int srow = tid >> 2, scg = (tid & 3) * 8;
  const int r = lane & 15, q = lane >> 4;
  const short* Ag = (const short*)A;
  const short* Bg = (const short*)B;
  for (int k0 = 0; k0 < K; k0 += BK){
    short8 va = {0,0,0,0,0,0,0,0};
    long ar = m0 + srow;
    if (ar < M) va = *(const short8*)(Ag + ar*K + k0 + scg);
    *(short8*)(&As[srow*LDT + scg]) = va;
    *(short8*)(&Bs[srow*LDT + scg]) = *(const short8*)(Bg + (long)(n0 + srow)*K + k0 + scg);
    __syncthreads();
    short8 a0 = *(const short8*)(&As[(wm      + r)*LDT + q*8]);
    short8 a1 = *(const short8*)(&As[(wm + 16 + r)*LDT + q*8]);
    short8 b0 = *(const short8*)(&Bs[(wn      + r)*LDT + q*8]);
    short8 b1 = *(const short8*)(&Bs[(wn + 16 + r)*LDT + q*8]);
    acc00 = __builtin_amdgcn_mfma_f32_16x16x32_bf16(a0, b0, acc00, 0, 0, 0);
    acc01 = __builtin_amdgcn_mfma_f32_16x16x32_bf16(a0, b1, acc01, 0, 0, 0);
    acc10 = __builtin_amdgcn_mfma_f32_16x16x32_bf16(a1, b0, acc10, 0, 0, 0);
    acc11 = __builtin_amdgcn_mfma_f32_16x16x32_bf16(a1, b1, acc11, 0, 0, 0);
    __syncthreads();
  }
  #pragma unroll
  for (int i=0;i<2;i++)
  #pragma unroll
  for (int j=0;j<2;j++){
    floatx4 av = (i==0) ? ((j==0)?acc00:acc01) : ((j==0)?acc10:acc11);
    int col = n0 + wn + j*16 + r;
    float bsv = bias[col];
    #pragma unroll
    for (int g=0; g<4; g++){
      long row = m0 + wm + i*16 + q*4 + g;
      if (row < M) C[row*(long)N + col] = av[g] + bsv;
    }
  }
}

// ---------------- attention: 1 wave per node, lane owns dims {2l,2l+1} as f16 pairs ----------------
// Edge loop unrolled x4: 4 independent KV-gather + score chains in flight per wave
// to cover L2-miss/L3 latency (counters showed VALUBusy 43%, HBM 32% -> latency-bound).
__global__ __launch_bounds__(256) void attn_agg(const unsigned* __restrict__ Qh,
     const uint2* __restrict__ KVh, const unsigned* __restrict__ Rh,
     const int* __restrict__ rowptr, const unsigned* __restrict__ srcet,
     unsigned* __restrict__ agg, int Nn){
  const int w = threadIdx.x >> 6, l = threadIdx.x & 63;
  const int n = blockIdx.x*4 + w;
  if (n >= Nn) return;
  hf2 q2 = u2h2(Qh[(long)n*64 + l]);
  int beg = rowptr[n], end = rowptr[n+1];
  float acc0 = 0.f, acc1 = 0.f, denom = 0.f;
  for (int c = beg; c < end; c += 64){
    int cnt = end - c; if (cnt > 64) cnt = 64;
    unsigned se_l = (c + l < end) ? srcet[c + l] : 0u;
    int j = 0;
    for (; j + 4 <= cnt; j += 4){
      unsigned se0 = __shfl(se_l, j+0);
      unsigned se1 = __shfl(se_l, j+1);
      unsigned se2 = __shfl(se_l, j+2);
      unsigned se3 = __shfl(se_l, j+3);
      uint2 kv0 = KVh[(long)(se0 & 0xFFFF)*64 + l];
      uint2 kv1 = KVh[(long)(se1 & 0xFFFF)*64 + l];
      uint2 kv2 = KVh[(long)(se2 & 0xFFFF)*64 + l];
      uint2 kv3 = KVh[(long)(se3 & 0xFFFF)*64 + l];
      unsigned r0 = Rh[(se0 >> 16)*64 + l];
      unsigned r1 = Rh[(se1 >> 16)*64 + l];
      unsigned r2 = Rh[(se2 >> 16)*64 + l];
      unsigned r3 = Rh[(se3 >> 16)*64 + l];
      hf2 kb0 = u2h2(kv0.x) + u2h2(r0);
      hf2 kb1 = u2h2(kv1.x) + u2h2(r1);
      hf2 kb2 = u2h2(kv2.x) + u2h2(r2);
      hf2 kb3 = u2h2(kv3.x) + u2h2(r3);
#if __has_builtin(__builtin_amdgcn_fdot2)
      float p0 = __builtin_amdgcn_fdot2(q2, kb0, 0.f, false);
      float p1 = __builtin_amdgcn_fdot2(q2, kb1, 0.f, false);
      float p2 = __builtin_amdgcn_fdot2(q2, kb2, 0.f, false);
      float p3 = __builtin_amdgcn_fdot2(q2, kb3, 0.f, false);
#else
      float p0 = fmaf((float)q2.y, (float)kb0.y, (float)q2.x * (float)kb0.x);
      float p1 = fmaf((float)q2.y, (float)kb1.y, (float)q2.x * (float)kb1.x);
      float p2 = fmaf((float)q2.y, (float)kb2.y, (float)q2.x * (float)kb2.x);
      float p3 = fmaf((float)q2.y, (float)kb3.y, (float)q2.x * (float)kb3.x);
#endif
      p0 += __shfl_xor(p0, 1); p1 += __shfl_xor(p1, 1);
      p2 += __shfl_xor(p2, 1); p3 += __shfl_xor(p3, 1);
      p0 += __shfl_xor(p0, 2); p1 += __shfl_xor(p1, 2);
      p2 += __shfl_xor(p2, 2); p3 += __shfl_xor(p3, 2);
      p0 += __shfl_xor(p0, 4); p1 += __shfl_xor(p1, 4);
      p2 += __shfl_xor(p2, 4); p3 += __shfl_xor(p3, 4);
      float e0 = __expf(p0 * 0.25f);
      float e1 = __expf(p1 * 0.25f);
      float e2 = __expf(p2 * 0.25f);
      float e3 = __expf(p3 * 0.25f);
      denom += e0; denom += e1; denom += e2; denom += e3;
      hf2 v0 = u2h2(kv0.y), v1 = u2h2(kv1.y), v2 = u2h2(kv2.y), v3 = u2h2(kv3.y);
      acc0 = fmaf(e0, (float)v0.x, acc0);
      acc1 = fmaf(e0, (float)v0.y, acc1);
      acc0 = fmaf(e1, (float)v1.x, acc0);
      acc1 = fmaf(e1, (float)v1.y, acc1);
      acc0 = fmaf(e2, (float)v2.x, acc0);
      acc1 = fmaf(e2, (float)v2.y, acc1);
      acc0 = fmaf(e3, (float)v3.x, acc0);
      acc1 = fmaf(e3, (float)v3.y, acc1);
    }
    for (; j < cnt; ++j){
      unsigned se = __shfl(se_l, j);
      int src = se & 0xFFFF;
      int et  = se >> 16;
      uint2 kv = KVh[(long)src*64 + l];
      hf2 kb = u2h2(kv.x) + u2h2(Rh[et*64 + l]);
#if __has_builtin(__builtin_amdgcn_fdot2)
      float p = __builtin_amdgcn_fdot2(q2, kb, 0.f, false);
#else
      float p = fmaf((float)q2.y, (float)kb.y, (float)q2.x * (float)kb.x);
#endif
      p += __shfl_xor(p, 1); p += __shfl_xor(p, 2); p += __shfl_xor(p, 4);
      float es = __expf(p * 0.25f);
      denom += es;
      hf2 v2 = u2h2(kv.y);
      acc0 = fmaf(es, (float)v2.x, acc0);
      acc1 = fmaf(es, (float)v2.y, acc1);
    }
  }
  float inv = 1.f / (denom + 1e-8f);
  unsigned out = ((unsigned)(unsigned short)bfbits(acc1 * inv) << 16)
               |  (unsigned)(unsigned short)bfbits(acc0 * inv);
  agg[(long)n*64 + l] = out;
}

// ---------------- residual + LN1: x = LN(nf + attn), out bf16 ----------------
__global__ __launch_bounds__(128) void ln_add1(const float* __restrict__ nf, const float* __restrict__ attn,
     const float* __restrict__ g, const float* __restrict__ b, bf16* __restrict__ xout){
  long n = blockIdx.x; int t = threadIdx.x;
  float y = nf[n*128 + t] + attn[n*128 + t];
  float s = y, s2 = y*y;
  #pragma unroll
  for (int off=32; off>0; off>>=1){ s += __shfl_xor(s, off); s2 += __shfl_xor(s2, off); }
  __shared__ float ps[4];
  if ((t & 63) == 0){ ps[(t>>6)*2] = s; ps[(t>>6)*2+1] = s2; }
  __syncthreads();
  float tot = ps[0] + ps[2], tot2 = ps[1] + ps[3];
  float mu = tot * (1.f/128.f);
  float var = tot2 * (1.f/128.f) - mu*mu;
  float rs = rsqrtf(var + 1e-5f);
  xout[n*128 + t] = f2b((y - mu)*rs*g[t] + b[t]);
}

// ---------------- fused FFN (MFMA), h split in 2 halves -> 68.6 KB LDS -> 2 blocks/CU ----------------
__global__ __launch_bounds__(256) void ffn_fused(const bf16* __restrict__ X, const bf16* __restrict__ W1,
    const float* __restrict__ b1, const bf16* __restrict__ W2, const float* __restrict__ b2,
    float* __restrict__ Out, int M){
  __shared__ short Xs[64*136];
  __shared__ short Hs[64*264];
  __shared__ short Ws[64*136];
  const int tid = threadIdx.x, lane = tid & 63, wave = tid >> 6;
  const int r = lane & 15, q = lane >> 4;
  const int wm = (wave >> 1) * 32, wn = (wave & 1) * 32;
  const long m0 = (long)blockIdx.x * 64;
  const short* Xg  = (const short*)X;
  const short* W1g = (const short*)W1;
  const short* W2g = (const short*)W2;
  #pragma unroll
  for (int c=0;c<4;c++){
    int idx = c*256 + tid, row = idx >> 4, ch = (idx & 15) * 8;
    short8 v = {0,0,0,0,0,0,0,0};
    long ar = m0 + row;
    if (ar < M) v = *(const short8*)(Xg + ar*128 + ch);
    *(short8*)(&Xs[row*136 + ch]) = v;
  }
  const int wn2 = (wave & 1) * 64;
  floatx4 o[2][4];
  #pragma unroll
  for (int i=0;i<2;i++)
  #pragma unroll
  for (int j=0;j<4;j++) o[i][j] = (floatx4){0.f,0.f,0.f,0.f};
  for (int half = 0; half < 2; ++half){
    const int hb = half * 256;
    for (int c0 = 0; c0 < 256; c0 += 64){
      #pragma unroll
      for (int c=0;c<4;c++){
        int idx = c*256 + tid, row = idx >> 4, ch = (idx & 15) * 8;
        *(short8*)(&Ws[row*136 + ch]) = *(const short8*)(W1g + (long)(hb + c0 + row)*128 + ch);
      }
      __syncthreads();
      floatx4 h00 = {0.f,0.f,0.f,0.f}, h01 = {0.f,0.f,0.f,0.f};
      floatx4 h10 = {0.f,0.f,0.f,0.f}, h11 = {0.f,0.f,0.f,0.f};
      #pragma unroll
      for (int k0 = 0; k0 < 128; k0 += 32){
        short8 a0 = *(const short8*)(&Xs[(wm      + r)*136 + k0 + q*8]);
        short8 a1 = *(const short8*)(&Xs[(wm + 16 + r)*136 + k0 + q*8]);
        short8 b0 = *(const short8*)(&Ws[(wn      + r)*136 + k0 + q*8]);
        short8 bv = *(const short8*)(&Ws[(wn + 16 + r)*136 + k0 + q*8]);
        h00 = __builtin_amdgcn_mfma_f32_16x16x32_bf16(a0, b0, h00, 0, 0, 0);
        h01 = __builtin_amdgcn_mfma_f32_16x16x32_bf16(a0, bv, h01, 0, 0, 0);
        h10 = __builtin_amdgcn_mfma_f32_16x16x32_bf16(a1, b0, h10, 0, 0, 0);
        h11 = __builtin_amdgcn_mfma_f32_16x16x32_bf16(a1, bv, h11, 0, 0, 0);
      }
      #pragma unroll
      for (int i=0;i<2;i++)
      #pragma unroll
      for (int j=0;j<2;j++){
        floatx4 av = (i==0) ? ((j==0)?h00:h01) : ((j==0)?h10:h11);
        int col = wn + j*16 + r;
        float bb = b1[hb + c0 + col];
        #pragma unroll
        for (int g=0; g<4; g++){
          int row = wm + i*16 + q*4 + g;
          float v = av[g] + bb;
          v = 0.5f * v * (1.f + erff(v * 0.70710678118f));   // exact GELU
          Hs[row*264 + c0 + col] = bfbits(v);
        }
      }
      __syncthreads();
    }
    for (int k0 = 0; k0 < 256; k0 += 32){
      #pragma unroll
      for (int c=0;c<2;c++){
        int idx = c*256 + tid, row = idx >> 2, ch = (idx & 3) * 8;
        *(short8*)(&Ws[row*40 + ch]) = *(const short8*)(W2g + (long)row*512 + hb + k0 + ch);
      }
      __syncthreads();
      short8 a0 = *(const short8*)(&Hs[(wm      + r)*264 + k0 + q*8]);
      short8 a1 = *(const short8*)(&Hs[(wm + 16 + r)*264 + k0 + q*8]);
      #pragma unroll
      for (int j=0;j<4;j++){
        short8 bj = *(const short8*)(&Ws[(wn2 + j*16 + r)*40 + q*8]);
        o[0][j] = __builtin_amdgcn_mfma_f32_16x16x32_bf16(a0, bj, o[0][j], 0, 0, 0);
        o[1][j] = __builtin_amdgcn_mfma_f32_16x16x32_bf16(a1, bj, o[1][j], 0, 0, 0);
      }
      __syncthreads();
    }
  }
  #pragma unroll
  for (int i=0;i<2;i++)
  #pragma unroll
  for (int j=0;j<4;j++){
    int col = wn2 + j*16 + r;
    float bb = b2[col];
    #pragma unroll
    for (int g=0; g<4; g++){
      long row = m0 + wm + i*16 + q*4 + g;
      if (row < M) Out[row*128 + col] = o[i][j][g] + bb;
    }
  }
}

// ---------------- residual + LN2: out = LN(x + ffo), f32 out ----------------
__global__ __launch_bounds__(128) void ln_add2(const bf16* __restrict__ X, const float* __restrict__ ffo,
     const float* __restrict__ g, const float* __restrict__ b, float* __restrict__ out){
  long n = blockIdx.x; int t = threadIdx.x;
  float y = b2f(X[n*128 + t]) + ffo[n*128 + t];
  float s = y, s2 = y*y;
  #pragma unroll
  for (int off=32; off>0; off>>=1){ s += __shfl_xor(s, off); s2 += __shfl_xor(s2, off); }
  __shared__ float ps[4];
  if ((t & 63) == 0){ ps[(t>>6)*2] = s; ps[(t>>6)*2+1] = s2; }
  __syncthreads();
  float tot = ps[0] + ps[2], tot2 = ps[1] + ps[3];
  float mu = tot * (1.f/128.f);
  float var = tot2 * (1.f/128.f) - mu*mu;
  float rs = rsqrtf(var + 1e-5f);
  out[n*128 + t] = (y - mu)*rs*g[t] + b[t];
}

// ---------------- relational interaction layer (R=100, naive f32) ----------------
__device__ __forceinline__ float dotf(const float* __restrict__ s, const float* __restrict__ w, int n){
  float acc = 0.f;
  const float4* w4 = (const float4*)w;
  #pragma unroll 4
  for (int j = 0; j < (n >> 2); ++j){
    float4 wv = w4[j];
    acc += s[4*j]*wv.x + s[4*j+1]*wv.y + s[4*j+2]*wv.z + s[4*j+3]*wv.w;
  }
  return acc;
}

__global__ __launch_bounds__(128) void rel_layer(const float* __restrict__ rel, const float* __restrict__ relW,
    const float* __restrict__ relb, const float* __restrict__ Wc, const float* __restrict__ bc,
    const float* __restrict__ gn, const float* __restrict__ bn, float* __restrict__ out){
  int rr = blockIdx.x, t = threadIdx.x;
  __shared__ float rrow[128];
  __shared__ float comb[512];
  rrow[t] = rel[(long)rr*128 + t];
  __syncthreads();
  #pragma unroll
  for (int k=0;k<4;k++){
    comb[k*128 + t] = dotf(rrow, relW + ((long)(k*128) + t)*128, 128) + relb[k*128 + t];
  }
  __syncthreads();
  float c2 = dotf(comb, Wc + (long)t*512, 512) + bc[t];
  float y = rrow[t] + c2;
  float s = y, s2 = y*y;
  #pragma unroll
  for (int off=32; off>0; off>>=1){ s += __shfl_xor(s, off); s2 += __shfl_xor(s2, off); }
  __shared__ float ps[4];
  if ((t & 63) == 0){ ps[(t>>6)*2] = s; ps[(t>>6)*2+1] = s2; }
  __syncthreads();
  float tot = ps[0] + ps[2], tot2 = ps[1] + ps[3];
  float mu = tot * (1.f/128.f);
  float var = tot2 * (1.f/128.f) - mu*mu;
  float rs = rsqrtf(var + 1e-5f);
  out[(long)rr*128 + t] = (y - mu)*rs*gn[t] + bn[t];
}

extern "C" void kernel_launch(void* const* d_in, const int* in_sizes, int n_in,
                              void* d_out, int out_size, void* d_ws, size_t ws_size,
                              hipStream_t stream){
  const int H = 128;
  auto S = [&](int i){ return in_sizes[i]; };
  bool ok = (n_in == 27);
  if (ok){
    ok = ok && S(1)==H && (S(0)%H)==0 && S(2)==2*S(3) && (S(4)%H)==0;
    ok = ok && S(5)==2*H*H && S(7)==2*H*H && S(9)==H*H && S(11)==H*H;
    ok = ok && S(17)==4*H*H && S(19)==4*H*H && S(21)==4*H*H && S(23)==4*H*H;
    ok = ok && out_size == S(0) + S(4);
  }
  if (!ok){
    fill_const<<<(out_size + 255)/256, 256, 0, stream>>>((float*)d_out, 100.0f, out_size);
    return;
  }

  const float* nf   = (const float*)d_in[0];
  const float* qe   = (const float*)d_in[1];
  const int*   ei   = (const int*)  d_in[2];
  const int*   ety  = (const int*)  d_in[3];
  const float* rel  = (const float*)d_in[4];
  const float* Wq   = (const float*)d_in[5];
  const float* bq   = (const float*)d_in[6];
  const float* Wk   = (const float*)d_in[7];
  const float* bk   = (const float*)d_in[8];
  const float* Wv   = (const float*)d_in[9];
  const float* bv   = (const float*)d_in[10];
  const float* Wo   = (const float*)d_in[11];
  const float* bo   = (const float*)d_in[12];
  const float* n1g  = (const float*)d_in[13];
  const float* n1b  = (const float*)d_in[14];
  const float* n2g  = (const float*)d_in[15];
  const float* n2b  = (const float*)d_in[16];
  const float* W1   = (const float*)d_in[17];
  const float* b1   = (const float*)d_in[18];
  const float* W2   = (const float*)d_in[19];
  const float* b2v  = (const float*)d_in[20];
  const float* relW = (const float*)d_in[21];
  const float* relbp= (const float*)d_in[22];
  const float* Wc   = (const float*)d_in[23];
  const float* bc   = (const float*)d_in[24];
  const float* rng  = (const float*)d_in[25];
  const float* rnb  = (const float*)d_in[26];

  const int N = in_sizes[0] / 128;
  const int E = in_sizes[2] / 2;
  const int R = in_sizes[4] / 128;

  char* ws = (char*)d_ws;
  size_t off = 0;
  auto alloc = [&](size_t bytes)->char*{
    char* p = ws + off; off = (off + bytes + 255) & ~(size_t)255; return p;
  };
  // regNA: nfb bf16 [N,128] -> aggp bf16 [N,128] (nfb dead after gemm_qkv)
  char*     regNA  = alloc((size_t)N * 256);
  // regKV: KVh uint2 [N,64] -> attn f32 [N,128] -> ffo f32 [N,128]
  char*     regKV  = alloc((size_t)N * 512);
  unsigned* Qh     = (unsigned*)alloc((size_t)N * 256);   // f16 pairs; dead after attn_agg
  bf16*     xlb    = (bf16*)    alloc((size_t)N * 256);
  bf16*     qeb    = (bf16*)    alloc(256);
  bf16*     Wcat   = (bf16*)    alloc((size_t)384*256*2);
  float*    bcat   = (float*)   alloc(384*4);
  bf16*     Wob    = (bf16*)    alloc((size_t)128*128*2);
  bf16*     W1b    = (bf16*)    alloc((size_t)512*128*2);
  bf16*     W2b    = (bf16*)    alloc((size_t)128*512*2);
  short*    Rh     = (short*)   alloc((size_t)R*128*2);   // rel embeddings f16
  int*      deg    = (int*)     alloc((size_t)N * 4);
  int*      rowptr = (int*)     alloc((size_t)(N+1) * 4);
  int*      cursor = (int*)     alloc((size_t)N * 4);
  unsigned* srcet  = (unsigned*)alloc((size_t)E * 4);
  const int NB = (N + 255) / 256;
  int*      bsum   = (int*)     alloc((size_t)NB * 4);

  if (off > ws_size){
    fill_const<<<(out_size + 255)/256, 256, 0, stream>>>((float*)d_out, 50.0f, out_size);
    return;
  }

  bf16*     nfb  = (bf16*)regNA;
  unsigned* aggp = (unsigned*)regNA;  // bf16 pairs, overlays nfb
  uint2*    KVh  = (uint2*)regKV;
  float*    attn = (float*)regKV;     // overlays KVh (dead after attn_agg)
  float*    ffo  = (float*)regKV;     // overlays attn (dead after ln_add1)
  float*    outx = (float*)d_out;
  float*    outr = (float*)d_out + (size_t)N*128;

  // conversions
  conv_f2b<<<(N*128 + 255)/256, 256, 0, stream>>>(nf, nfb, N*128);
  conv_f2b<<<1, 128, 0, stream>>>(qe, qeb, 128);
  build_wcat<<<(384*256 + 255)/256, 256, 0, stream>>>(Wq, Wk, Wv, bq, bk, bv, Wcat, bcat);
  conv_f2b<<<(128*128 + 255)/256, 256, 0, stream>>>(Wo, Wob, 128*128);
  conv_f2b<<<(512*128 + 255)/256, 256, 0, stream>>>(W1, W1b, 512*128);
  conv_f2b<<<(128*512 + 255)/256, 256, 0, stream>>>(W2, W2b, 128*512);
  conv_f2h<<<(R*128 + 255)/256, 256, 0, stream>>>(rel, Rh, R*128);

  // CSR (hierarchical scan: per-block reduce -> scan block sums -> per-block scan)
  hipMemsetAsync(deg, 0, (size_t)N*4, stream);
  edge_hist<<<(E + 255)/256, 256, 0, stream>>>(ei, E, deg);
  scan_p1<<<NB, 256, 0, stream>>>(deg, N, bsum);
  scan_p2<<<1, 1024, 0, stream>>>(bsum, NB, E, rowptr, N);
  scan_p3<<<NB, 256, 0, stream>>>(deg, bsum, N, rowptr, cursor);
  edge_scatter<<<(E + 255)/256, 256, 0, stream>>>(ei, ety, E, cursor, srcet);

  // pipeline
  dim3 g1((N + 63)/64, 6);
  gemm_qkv<<<g1, 256, 0, stream>>>(nfb, qeb, Wcat, bcat, (short*)Qh, (short*)KVh, N);
  attn_agg<<<(N + 3)/4, 256, 0, stream>>>(Qh, KVh, (const unsigned*)Rh, rowptr, srcet, aggp, N);
  dim3 g2((N + 63)/64, 2);
  gemm_bt<<<g2, 256, 0, stream>>>((const bf16*)aggp, Wob, bo, attn, N, 128, 128);
  ln_add1<<<N, 128, 0, stream>>>(nf, attn, n1g, n1b, xlb);
  ffn_fused<<<(N + 63)/64, 256, 0, stream>>>(xlb, W1b, b1, W2b, b2v, ffo, N);
  ln_add2<<<N, 128, 0, stream>>>(xlb, ffo, n2g, n2b, outx);
  rel_layer<<<R, 128, 0, stream>>>(rel, relW, relbp, Wc, bc, rng, rnb, outr);
}